// Round 6
// baseline (1730.803 us; speedup 1.0000x reference)
//
#include <hip/hip_runtime.h>

// VQ nearest-codebook. Reference = numpy float32 pipeline (verified bit-exact
// R2). fp16 MFMA GEMM (K=256): s*2^20 = en*2^20 - 128*acc, where
// acc = fp16(z).fp16(e*2^14) accumulated fp32 (score error sigma ~3e-7,
// far below the 84-unit resolve window). Per-row running top-3 keys per
// 512-col group, exact numpy-f32 re-score of window candidates.
// R6: M-tile 256 (512-thr blocks, 3 blocks/CU), fused prep launches.
//
// ws: zh 8MB | eh 8MB | zn 64K | en 64K | part 6.3MB

#define NQ 16384
#define NE 16384
#define DIM 256

typedef __attribute__((ext_vector_type(8))) _Float16 half8;
typedef __attribute__((ext_vector_type(4))) float floatx4;

__device__ __forceinline__ float fm(float a, float b) { return __fmul_rn(a, b); }
__device__ __forceinline__ float fa(float a, float b) { return __fadd_rn(a, b); }
__device__ __forceinline__ float fs(float a, float b) { return __fsub_rn(a, b); }

#define GLOAD_LDS16(gp, lp)                                                  \
    __builtin_amdgcn_global_load_lds(                                        \
        (const __attribute__((address_space(1))) void*)(gp),                 \
        (__attribute__((address_space(3))) void*)(lp), 16, 0, 0)

// ---------- fused: transpose z -> zh (fp16)  +  exact numpy znorm ----------
// blocks [0,4096): 32x32 transpose tiles; blocks [4096,4160): znorm rows
__global__ __launch_bounds__(256) void prep_z(const float* __restrict__ z,
                                              _Float16* __restrict__ zh,
                                              float* __restrict__ zn) {
    const int bid = blockIdx.x;
    const int t = threadIdx.x;
    if (bid < 4096) {
        __shared__ float tile[32][33];
        const int b  = bid >> 8;
        const int c0 = ((bid >> 5) & 7) * 32;
        const int n0 = (bid & 31) * 32;
        const int tx = t & 31, ty = t >> 5;           // 32 x 8
        const float* zb = z + (size_t)b * 256 * 1024;
        #pragma unroll
        for (int j = 0; j < 32; j += 8)
            tile[ty + j][tx] = zb[(size_t)(c0 + ty + j) * 1024 + n0 + tx];
        __syncthreads();
        #pragma unroll
        for (int j = 0; j < 32; j += 8)
            zh[(size_t)(b * 1024 + n0 + ty + j) * 256 + c0 + tx] =
                (_Float16)tile[tx][ty + j];
    } else {
        // numpy pairwise_sum(x*x): strided z row (element c at z[b][c][hw])
        const int row = (bid - 4096) * 256 + t;
        const float* p = z + ((size_t)(row >> 10) * 256) * 1024 + (row & 1023);
        float half_[2];
        #pragma unroll
        for (int h = 0; h < 2; ++h) {
            const int c0 = h * 128;
            float r[8], v;
            #pragma unroll
            for (int j = 0; j < 8; j++) { v = p[(size_t)(c0 + j) << 10]; r[j] = fm(v, v); }
            #pragma unroll
            for (int i = 8; i < 128; i += 8)
                #pragma unroll
                for (int j = 0; j < 8; j++) {
                    v = p[(size_t)(c0 + i + j) << 10];
                    r[j] = fa(r[j], fm(v, v));
                }
            half_[h] = fa(fa(fa(r[0], r[1]), fa(r[2], r[3])),
                          fa(fa(r[4], r[5]), fa(r[6], r[7])));
        }
        zn[row] = fa(half_[0], half_[1]);
    }
}

// ---------- fused: codebook -> fp16(e*2^14)  +  exact numpy enorm ----------
__global__ __launch_bounds__(256) void prep_e(const float* __restrict__ cb,
                                              _Float16* __restrict__ eh,
                                              float* __restrict__ en) {
    const int bid = blockIdx.x;
    const int t = threadIdx.x;
    if (bid < 4096) {
        const size_t i = ((size_t)bid * 256 + t) * 4;
        const float4 v = *(const float4*)(cb + i);
        _Float16 o[4] = { (_Float16)(v.x * 16384.0f), (_Float16)(v.y * 16384.0f),
                          (_Float16)(v.z * 16384.0f), (_Float16)(v.w * 16384.0f) };
        *(ushort4*)(eh + i) = *(const ushort4*)o;
    } else {
        const int row = (bid - 4096) * 256 + t;
        const float* p = cb + (size_t)row * DIM;
        float half_[2];
        #pragma unroll
        for (int h = 0; h < 2; ++h) {
            const float* q = p + h * 128;
            float r[8];
            #pragma unroll
            for (int j = 0; j < 8; j++) r[j] = fm(q[j], q[j]);
            #pragma unroll
            for (int i = 8; i < 128; i += 8)
                #pragma unroll
                for (int j = 0; j < 8; j++) r[j] = fa(r[j], fm(q[i + j], q[i + j]));
            half_[h] = fa(fa(fa(r[0], r[1]), fa(r[2], r[3])),
                          fa(fa(r[4], r[5]), fa(r[6], r[7])));
        }
        en[row] = fa(half_[0], half_[1]);
    }
}

// sorted-triple merge: (a,b sorted ascending) -> top-3 of union in a
__device__ __forceinline__ void merge3(unsigned& a0, unsigned& a1, unsigned& a2,
                                       unsigned b0, unsigned b1, unsigned b2) {
    const unsigned m0 = min(a0, b0);
    const unsigned x  = max(a0, b0);
    const unsigned p  = min(a1, b1);
    const unsigned q  = max(a1, b1);
    const unsigned m1 = min(x, p);
    const unsigned m2 = min(max(x, p), min(q, min(a2, b2)));
    a0 = m0; a1 = m1; a2 = m2;
}

// ---------------- MFMA GEMM (K=256 fp16) + per-row running top-3 keys ----------------
// grid (64 row-tiles of 256, 32 col-groups of 512); block 512 = 8 waves (4x2 of 64x64)
__global__ __launch_bounds__(512, 6) void gemm_top3(
    const _Float16* __restrict__ zh, const _Float16* __restrict__ eh,
    const float* __restrict__ en, unsigned* __restrict__ part)
{
    __shared__ __align__(16) _Float16 Ab[256 * 64];  // 32 KB; [m][g'] g'=g^(m&7)
    __shared__ __align__(16) _Float16 Bb[128 * 64];  // 16 KB
    unsigned* mbuf = (unsigned*)&Ab[0];              // overlay: 256*2*3 u32 = 6 KB

    const int t = threadIdx.x;
    const int lane = t & 63, w = t >> 6;             // 8 waves
    const int wr = w >> 1, wc = w & 1;               // 4 x 2 wave grid
    const int q4 = lane >> 4, c4 = lane & 15;
    const int m0 = blockIdx.x * 256;
    const int g0 = blockIdx.y * 512;

    unsigned trip[16][3];                     // running sorted top-3 per (i,r)
    #pragma unroll
    for (int s = 0; s < 16; ++s)
        trip[s][0] = trip[s][1] = trip[s][2] = 0xFFFFFFFFu;

    // per-thread DMA slot geometry (constant across iterations)
    int smA[4], sgA[4], smB[2], sgB[2];
    #pragma unroll
    for (int p = 0; p < 4; ++p) {
        const int s = p * 512 + t;
        smA[p] = s >> 3;
        sgA[p] = (s & 7) ^ (smA[p] & 7);
    }
    #pragma unroll
    for (int p = 0; p < 2; ++p) {
        const int s = p * 512 + t;
        smB[p] = s >> 3;
        sgB[p] = (s & 7) ^ (smB[p] & 7);
    }
    const int ldsb = w * 64 * 8;              // wave-uniform LDS slot base (elements)

    for (int sub = 0; sub < 4; ++sub) {
        const int n0 = g0 + sub * 128;
        floatx4 acc[4][4];
        #pragma unroll
        for (int i = 0; i < 4; i++)
            #pragma unroll
            for (int j = 0; j < 4; j++) acc[i][j] = (floatx4){0.f, 0.f, 0.f, 0.f};

        for (int kb4 = 0; kb4 < 4; ++kb4) {
            const int kb = kb4 * 64;
            #pragma unroll
            for (int p = 0; p < 4; ++p)
                GLOAD_LDS16(zh + (size_t)(m0 + smA[p]) * 256 + kb + sgA[p] * 8,
                            &Ab[(p * 512) * 8 + ldsb]);
            #pragma unroll
            for (int p = 0; p < 2; ++p)
                GLOAD_LDS16(eh + (size_t)(n0 + smB[p]) * 256 + kb + sgB[p] * 8,
                            &Bb[(p * 512) * 8 + ldsb]);
            __syncthreads();
            #pragma unroll
            for (int kk = 0; kk < 2; ++kk) {
                half8 a[4], b[4];
                #pragma unroll
                for (int i = 0; i < 4; ++i) {
                    const int m  = wr * 64 + i * 16 + c4;
                    const int gs = (kk * 4 + q4) ^ (m & 7);
                    a[i] = *(const half8*)&Ab[(size_t)(m * 8 + gs) * 8];
                }
                #pragma unroll
                for (int j = 0; j < 4; ++j) {
                    const int n  = wc * 64 + j * 16 + c4;
                    const int gs = (kk * 4 + q4) ^ (n & 7);
                    b[j] = *(const half8*)&Bb[(size_t)(n * 8 + gs) * 8];
                }
                #pragma unroll
                for (int i = 0; i < 4; ++i)
                    #pragma unroll
                    for (int j = 0; j < 4; ++j)
                        acc[i][j] = __builtin_amdgcn_mfma_f32_16x16x32_f16(
                            a[i], b[j], acc[i][j], 0, 0, 0);
            }
            __syncthreads();
        }

        // ---- epilogue: 3-op keys + running top-3 (register-only) ----
        float en2[4]; unsigned cp[4];
        #pragma unroll
        for (int j = 0; j < 4; ++j) {
            const int col = n0 + wc * 64 + j * 16 + c4;
            en2[j] = en[col] * 1048576.0f;                 // en * 2^20
            cp[j]  = (131072u << 14) + (unsigned)col;
        }
        #pragma unroll
        for (int i = 0; i < 4; ++i)
            #pragma unroll
            for (int r = 0; r < 4; ++r) {
                // s*2^20 = en*2^20 - 2*2^-14*2^20*acc = fma(acc,-128,en2)
                const int v0 = (int)__builtin_fmaf(acc[i][0][r], -128.0f, en2[0]);
                const int v1 = (int)__builtin_fmaf(acc[i][1][r], -128.0f, en2[1]);
                const int v2 = (int)__builtin_fmaf(acc[i][2][r], -128.0f, en2[2]);
                const int v3 = (int)__builtin_fmaf(acc[i][3][r], -128.0f, en2[3]);
                const unsigned k0 = ((unsigned)v0 << 14) + cp[0];
                const unsigned k1 = ((unsigned)v1 << 14) + cp[1];
                const unsigned k2 = ((unsigned)v2 << 14) + cp[2];
                const unsigned k3 = ((unsigned)v3 << 14) + cp[3];
                const unsigned l01 = min(k0, k1), h01 = max(k0, k1);
                const unsigned l23 = min(k2, k3), h23 = max(k2, k3);
                const unsigned s0  = min(l01, l23);
                const unsigned m1  = max(l01, l23), m2 = min(h01, h23);
                const unsigned s1  = min(m1, m2),  s2 = max(m1, m2);
                merge3(trip[i * 4 + r][0], trip[i * 4 + r][1], trip[i * 4 + r][2],
                       s0, s1, s2);
            }
    }

    // ---- one cross-lane merge over c4 lanes (masks 1,2,4,8) ----
    // (after the sub loop's final barrier, Ab is dead -> mbuf overlay is safe)
    #pragma unroll
    for (int s = 0; s < 16; ++s) {
        unsigned t0 = trip[s][0], t1 = trip[s][1], t2 = trip[s][2];
        #pragma unroll
        for (int msk = 1; msk < 16; msk <<= 1) {
            const unsigned u0 = (unsigned)__shfl_xor((int)t0, msk, 64);
            const unsigned u1 = (unsigned)__shfl_xor((int)t1, msk, 64);
            const unsigned u2 = (unsigned)__shfl_xor((int)t2, msk, 64);
            merge3(t0, t1, t2, u0, u1, u2);
        }
        if (c4 < 3) {
            const int row = wr * 64 + (s >> 2) * 16 + q4 * 4 + (s & 3);
            mbuf[(row * 2 + wc) * 3 + c4] = (c4 == 0) ? t0 : ((c4 == 1) ? t1 : t2);
        }
    }
    __syncthreads();
    if (t < 256) {
        unsigned a0 = mbuf[(t * 2 + 0) * 3 + 0];
        unsigned a1 = mbuf[(t * 2 + 0) * 3 + 1];
        unsigned a2 = mbuf[(t * 2 + 0) * 3 + 2];
        merge3(a0, a1, a2, mbuf[(t * 2 + 1) * 3 + 0],
               mbuf[(t * 2 + 1) * 3 + 1], mbuf[(t * 2 + 1) * 3 + 2]);
        unsigned* pp = part + (size_t)(m0 + t) * 96 + blockIdx.y * 3;
        pp[0] = a0; pp[1] = a1; pp[2] = a2;
    }
}

// ---------------- resolve: window-candidates -> exact numpy re-score ----------------
__global__ __launch_bounds__(256) void resolve(
    const unsigned* __restrict__ part, const float* __restrict__ z,
    const float* __restrict__ cb, const float* __restrict__ zn,
    const float* __restrict__ en, float* __restrict__ out_zq,
    float* __restrict__ out_idx)
{
    const int w = threadIdx.x >> 6, lane = threadIdx.x & 63;
    const int row = blockIdx.x * 4 + w;
    __shared__ unsigned candbuf[4][16];

    const unsigned* pr = part + (size_t)row * 96;
    const unsigned k1 = pr[lane];
    const unsigned k2 = (lane < 32) ? pr[64 + lane] : 0xFFFFFFFFu;
    unsigned vm = min(k1, k2);
    #pragma unroll
    for (int m = 1; m < 64; m <<= 1)
        vm = min(vm, (unsigned)__shfl_xor((int)vm, m, 64));
    const unsigned vlim = (vm >> 14) + 84u;
    const bool s1 = (k1 >> 14) <= vlim;
    const bool s2 = (lane < 32) && ((k2 >> 14) <= vlim);
    const unsigned long long b1 = __ballot(s1);
    const unsigned long long b2 = __ballot(s2);
    const unsigned long long below = (1ull << lane) - 1ull;
    const int pos1 = __popcll(b1 & below);
    const int pos2 = __popcll(b1) + __popcll(b2 & below);
    int ncand = __popcll(b1) + __popcll(b2);
    if (ncand > 16) ncand = 16;

    if (lane < 16) candbuf[w][lane] = 0;
    __syncthreads();
    if (s1 && pos1 < 16) candbuf[w][pos1] = k1 & 16383u;
    if (s2 && pos2 < 16) candbuf[w][pos2] = k2 & 16383u;
    __syncthreads();

    const int ci = lane >> 2, l = lane & 3;
    const bool act = ci < ncand;
    const unsigned idxc = candbuf[w][ci];
    const float* zb  = z + ((size_t)(row >> 10) * 256) * 1024 + (row & 1023);
    const float* cbr = cb + (size_t)idxc * 256;
    // numpy einsum SSE chain, lane l of 4: elements ch*16 + v*4 + l, v desc
    float s = 0.f;
    #pragma unroll
    for (int ch = 0; ch < 16; ++ch)
        #pragma unroll
        for (int v = 3; v >= 0; --v) {
            const int cd = ch * 16 + v * 4 + l;
            s = fa(fm(zb[(size_t)cd << 10], cbr[cd]), s);
        }
    const int base = lane & ~3;
    const float s0 = __shfl(s, base + 0, 64);
    const float sA = __shfl(s, base + 1, 64);
    const float sB = __shfl(s, base + 2, 64);
    const float sC = __shfl(s, base + 3, 64);
    const float cross = fa(fa(s0, sA), fa(sB, sC));
    const float d = fs(fa(zn[row], en[idxc]), fm(2.0f, cross));
    unsigned long long key = act
        ? (((unsigned long long)__float_as_uint(d) << 32) | idxc) : ~0ull;
    #pragma unroll
    for (int m = 1; m < 64; m <<= 1) {
        const unsigned long long o =
            (unsigned long long)__shfl_xor((long long)key, m, 64);
        if (o < key) key = o;
    }
    const int widx = (int)(key & 0xFFFFFFFFu);
    *(float4*)(out_zq + (size_t)row * 256 + lane * 4) =
        *(const float4*)(cb + (size_t)widx * 256 + lane * 4);
    if (lane == 0) out_idx[row] = (float)widx;
}

extern "C" void kernel_launch(void* const* d_in, const int* in_sizes, int n_in,
                              void* d_out, int out_size, void* d_ws, size_t ws_size,
                              hipStream_t stream) {
    const float* z  = (const float*)d_in[0];   // [16][256][32][32]
    const float* cb = (const float*)d_in[1];   // [16384][256]
    float* out = (float*)d_out;                // z_q (4194304 f32) then idx (16384 as f32)

    char* ws = (char*)d_ws;
    _Float16* zh = (_Float16*)ws;                                  // 8 MB
    _Float16* eh = (_Float16*)(ws + (size_t)8388608);              // 8 MB
    float* zn  = (float*)(ws + (size_t)16777216);                  // 64 KB
    float* en  = (float*)(ws + (size_t)16842752);                  // 64 KB
    unsigned* part = (unsigned*)(ws + (size_t)16908288);           // 6.29 MB

    prep_z<<<4160, 256, 0, stream>>>(z, zh, zn);
    prep_e<<<4160, 256, 0, stream>>>(cb, eh, en);
    gemm_top3<<<dim3(64, 32), 512, 0, stream>>>(zh, eh, en, part);
    resolve<<<4096, 256, 0, stream>>>(part, z, cb, zn, en, out,
                                      out + (size_t)NQ * DIM);
}

// Round 7
// 375.147 us; speedup vs baseline: 4.6137x; 4.6137x over previous
//
#include <hip/hip_runtime.h>

// VQ nearest-codebook. Reference = numpy float32 pipeline (verified bit-exact
// R2). fp16 MFMA GEMM (K=256): s*2^20 = en*2^20 - 128*acc, where
// acc = fp16(z).fp16(e*2^14) accumulated fp32 (score error sigma ~3e-7,
// far below the 84-unit resolve window). Per-row running top-3 keys per
// 512-col group, exact numpy-f32 re-score of window candidates.
// R7: back to 256-thr/M=128 blocks (R6's 512-thr variant hit the 85-reg
// launch-bounds cap and spilled to scratch: VGPR 40, 4 GB scratch traffic).
// New: flat (sub,kb4) loop + ping-pong LDS + 1 barrier/chunk + DMA prefetch
// issued before compute, overlapping sub-boundary epilogues.
//
// ws: zh 8MB | eh 8MB | zn 64K | en 64K | part 6.3MB

#define NQ 16384
#define NE 16384
#define DIM 256

typedef __attribute__((ext_vector_type(8))) _Float16 half8;
typedef __attribute__((ext_vector_type(4))) float floatx4;

__device__ __forceinline__ float fm(float a, float b) { return __fmul_rn(a, b); }
__device__ __forceinline__ float fa(float a, float b) { return __fadd_rn(a, b); }
__device__ __forceinline__ float fs(float a, float b) { return __fsub_rn(a, b); }

#define GLOAD_LDS16(gp, lp)                                                  \
    __builtin_amdgcn_global_load_lds(                                        \
        (const __attribute__((address_space(1))) void*)(gp),                 \
        (__attribute__((address_space(3))) void*)(lp), 16, 0, 0)

// ---------- fused: transpose z -> zh (fp16)  +  exact numpy znorm ----------
// blocks [0,4096): 32x32 transpose tiles; blocks [4096,4160): znorm rows
__global__ __launch_bounds__(256) void prep_z(const float* __restrict__ z,
                                              _Float16* __restrict__ zh,
                                              float* __restrict__ zn) {
    const int bid = blockIdx.x;
    const int t = threadIdx.x;
    if (bid < 4096) {
        __shared__ float tile[32][33];
        const int b  = bid >> 8;
        const int c0 = ((bid >> 5) & 7) * 32;
        const int n0 = (bid & 31) * 32;
        const int tx = t & 31, ty = t >> 5;           // 32 x 8
        const float* zb = z + (size_t)b * 256 * 1024;
        #pragma unroll
        for (int j = 0; j < 32; j += 8)
            tile[ty + j][tx] = zb[(size_t)(c0 + ty + j) * 1024 + n0 + tx];
        __syncthreads();
        #pragma unroll
        for (int j = 0; j < 32; j += 8)
            zh[(size_t)(b * 1024 + n0 + ty + j) * 256 + c0 + tx] =
                (_Float16)tile[tx][ty + j];
    } else {
        // numpy pairwise_sum(x*x): strided z row (element c at z[b][c][hw])
        const int row = (bid - 4096) * 256 + t;
        const float* p = z + ((size_t)(row >> 10) * 256) * 1024 + (row & 1023);
        float half_[2];
        #pragma unroll
        for (int h = 0; h < 2; ++h) {
            const int c0 = h * 128;
            float r[8], v;
            #pragma unroll
            for (int j = 0; j < 8; j++) { v = p[(size_t)(c0 + j) << 10]; r[j] = fm(v, v); }
            #pragma unroll
            for (int i = 8; i < 128; i += 8)
                #pragma unroll
                for (int j = 0; j < 8; j++) {
                    v = p[(size_t)(c0 + i + j) << 10];
                    r[j] = fa(r[j], fm(v, v));
                }
            half_[h] = fa(fa(fa(r[0], r[1]), fa(r[2], r[3])),
                          fa(fa(r[4], r[5]), fa(r[6], r[7])));
        }
        zn[row] = fa(half_[0], half_[1]);
    }
}

// ---------- fused: codebook -> fp16(e*2^14)  +  exact numpy enorm ----------
__global__ __launch_bounds__(256) void prep_e(const float* __restrict__ cb,
                                              _Float16* __restrict__ eh,
                                              float* __restrict__ en) {
    const int bid = blockIdx.x;
    const int t = threadIdx.x;
    if (bid < 4096) {
        const size_t i = ((size_t)bid * 256 + t) * 4;
        const float4 v = *(const float4*)(cb + i);
        _Float16 o[4] = { (_Float16)(v.x * 16384.0f), (_Float16)(v.y * 16384.0f),
                          (_Float16)(v.z * 16384.0f), (_Float16)(v.w * 16384.0f) };
        *(ushort4*)(eh + i) = *(const ushort4*)o;
    } else {
        const int row = (bid - 4096) * 256 + t;
        const float* p = cb + (size_t)row * DIM;
        float half_[2];
        #pragma unroll
        for (int h = 0; h < 2; ++h) {
            const float* q = p + h * 128;
            float r[8];
            #pragma unroll
            for (int j = 0; j < 8; j++) r[j] = fm(q[j], q[j]);
            #pragma unroll
            for (int i = 8; i < 128; i += 8)
                #pragma unroll
                for (int j = 0; j < 8; j++) r[j] = fa(r[j], fm(q[i + j], q[i + j]));
            half_[h] = fa(fa(fa(r[0], r[1]), fa(r[2], r[3])),
                          fa(fa(r[4], r[5]), fa(r[6], r[7])));
        }
        en[row] = fa(half_[0], half_[1]);
    }
}

// sorted-triple merge: (a,b sorted ascending) -> top-3 of union in a
__device__ __forceinline__ void merge3(unsigned& a0, unsigned& a1, unsigned& a2,
                                       unsigned b0, unsigned b1, unsigned b2) {
    const unsigned m0 = min(a0, b0);
    const unsigned x  = max(a0, b0);
    const unsigned p  = min(a1, b1);
    const unsigned q  = max(a1, b1);
    const unsigned m1 = min(x, p);
    const unsigned m2 = min(max(x, p), min(q, min(a2, b2)));
    a0 = m0; a1 = m1; a2 = m2;
}

// ---------------- MFMA GEMM (K=256 fp16) + per-row running top-3 keys ----------------
// grid (128 row-tiles, 32 col-groups of 512); block 256 = 4 waves (2x2 of 64x64).
// Flat 16-iter (sub,kb4) loop, ping-pong LDS (2 x [A 16KB | B 16KB]), one
// barrier per chunk, DMA for chunk i+1 issued before compute of chunk i.
__global__ __launch_bounds__(256, 2) void gemm_top3(
    const _Float16* __restrict__ zh, const _Float16* __restrict__ eh,
    const float* __restrict__ en, unsigned* __restrict__ part)
{
    __shared__ __align__(16) _Float16 lds[2][16384];  // [buf][A 8192 | B 8192]
    unsigned* mbuf = (unsigned*)&lds[0][0];           // overlay after last compute

    const int t = threadIdx.x;
    const int lane = t & 63, w = t >> 6;
    const int wr = w >> 1, wc = w & 1;
    const int q4 = lane >> 4, c4 = lane & 15;
    const int m0 = blockIdx.x * 128;
    const int g0 = blockIdx.y * 512;

    unsigned trip[16][3];                     // running sorted top-3 per (i,r)
    #pragma unroll
    for (int s = 0; s < 16; ++s)
        trip[s][0] = trip[s][1] = trip[s][2] = 0xFFFFFFFFu;

    // per-thread DMA slot geometry (A and B tiles are both 128x64 -> 1024
    // 16B slots, 4 per thread)
    int sm[4], sg[4];
    #pragma unroll
    for (int p = 0; p < 4; ++p) {
        const int s = p * 256 + t;
        sm[p] = s >> 3;
        sg[p] = (s & 7) ^ (sm[p] & 7);
    }
    const int ldsb = w * 64 * 8;              // wave-uniform LDS slot base (elements)

    // prefetch chunk 0 into buf 0
    {
        const int n0 = g0, kb = 0;
        #pragma unroll
        for (int p = 0; p < 4; ++p) {
            GLOAD_LDS16(zh + (size_t)(m0 + sm[p]) * 256 + kb + sg[p] * 8,
                        &lds[0][(p * 256) * 8 + ldsb]);
            GLOAD_LDS16(eh + (size_t)(n0 + sm[p]) * 256 + kb + sg[p] * 8,
                        &lds[0][8192 + (p * 256) * 8 + ldsb]);
        }
    }

    floatx4 acc[4][4];
    for (int it = 0; it < 16; ++it) {
        const int sub = it >> 2;
        const int buf = it & 1;
        const int n0 = g0 + sub * 128;

        if ((it & 3) == 0) {
            #pragma unroll
            for (int i = 0; i < 4; i++)
                #pragma unroll
                for (int j = 0; j < 4; j++) acc[i][j] = (floatx4){0.f, 0.f, 0.f, 0.f};
        }

        __syncthreads();   // drains DMA(it) [vmcnt] + all waves done reading buf^1

        if (it + 1 < 16) {
            const int subn = (it + 1) >> 2;
            const int kbn  = ((it + 1) & 3) * 64;
            const int n0n  = g0 + subn * 128;
            _Float16* dst = &lds[buf ^ 1][0];
            #pragma unroll
            for (int p = 0; p < 4; ++p) {
                GLOAD_LDS16(zh + (size_t)(m0 + sm[p]) * 256 + kbn + sg[p] * 8,
                            dst + (p * 256) * 8 + ldsb);
                GLOAD_LDS16(eh + (size_t)(n0n + sm[p]) * 256 + kbn + sg[p] * 8,
                            dst + 8192 + (p * 256) * 8 + ldsb);
            }
        }

        const _Float16* Ab = &lds[buf][0];
        const _Float16* Bb = &lds[buf][8192];
        #pragma unroll
        for (int kk = 0; kk < 2; ++kk) {
            half8 a[4], b[4];
            #pragma unroll
            for (int i = 0; i < 4; ++i) {
                const int m  = wr * 64 + i * 16 + c4;
                const int gs = (kk * 4 + q4) ^ (m & 7);
                a[i] = *(const half8*)&Ab[(size_t)(m * 8 + gs) * 8];
            }
            #pragma unroll
            for (int j = 0; j < 4; ++j) {
                const int n  = wc * 64 + j * 16 + c4;
                const int gs = (kk * 4 + q4) ^ (n & 7);
                b[j] = *(const half8*)&Bb[(size_t)(n * 8 + gs) * 8];
            }
            #pragma unroll
            for (int i = 0; i < 4; ++i)
                #pragma unroll
                for (int j = 0; j < 4; ++j)
                    acc[i][j] = __builtin_amdgcn_mfma_f32_16x16x32_f16(
                        a[i], b[j], acc[i][j], 0, 0, 0);
        }

        if ((it & 3) == 3) {
            // ---- epilogue: 3-op keys + running top-3 (register-only) ----
            // (overlaps the already-issued DMA of the next sub's first chunk)
            float en2[4]; unsigned cp[4];
            #pragma unroll
            for (int j = 0; j < 4; ++j) {
                const int col = n0 + wc * 64 + j * 16 + c4;
                en2[j] = en[col] * 1048576.0f;                 // en * 2^20
                cp[j]  = (131072u << 14) + (unsigned)col;
            }
            #pragma unroll
            for (int i = 0; i < 4; ++i)
                #pragma unroll
                for (int r = 0; r < 4; ++r) {
                    // s*2^20 = en*2^20 - 2*2^-14*2^20*acc = fma(acc,-128,en2)
                    const int v0 = (int)__builtin_fmaf(acc[i][0][r], -128.0f, en2[0]);
                    const int v1 = (int)__builtin_fmaf(acc[i][1][r], -128.0f, en2[1]);
                    const int v2 = (int)__builtin_fmaf(acc[i][2][r], -128.0f, en2[2]);
                    const int v3 = (int)__builtin_fmaf(acc[i][3][r], -128.0f, en2[3]);
                    const unsigned k0 = ((unsigned)v0 << 14) + cp[0];
                    const unsigned k1 = ((unsigned)v1 << 14) + cp[1];
                    const unsigned k2 = ((unsigned)v2 << 14) + cp[2];
                    const unsigned k3 = ((unsigned)v3 << 14) + cp[3];
                    const unsigned l01 = min(k0, k1), h01 = max(k0, k1);
                    const unsigned l23 = min(k2, k3), h23 = max(k2, k3);
                    const unsigned s0  = min(l01, l23);
                    const unsigned m1  = max(l01, l23), m2 = min(h01, h23);
                    const unsigned s1  = min(m1, m2),  s2 = max(m1, m2);
                    merge3(trip[i * 4 + r][0], trip[i * 4 + r][1], trip[i * 4 + r][2],
                           s0, s1, s2);
                }
        }
    }

    // ---- one cross-lane merge over c4 lanes (masks 1,2,4,8) ----
    // mbuf overlays lds[0]: last compute (it=15) read lds[1]; lds[0] dead.
    #pragma unroll
    for (int s = 0; s < 16; ++s) {
        unsigned t0 = trip[s][0], t1 = trip[s][1], t2 = trip[s][2];
        #pragma unroll
        for (int msk = 1; msk < 16; msk <<= 1) {
            const unsigned u0 = (unsigned)__shfl_xor((int)t0, msk, 64);
            const unsigned u1 = (unsigned)__shfl_xor((int)t1, msk, 64);
            const unsigned u2 = (unsigned)__shfl_xor((int)t2, msk, 64);
            merge3(t0, t1, t2, u0, u1, u2);
        }
        if (c4 < 3) {
            const int row = wr * 64 + (s >> 2) * 16 + q4 * 4 + (s & 3);
            mbuf[(row * 2 + wc) * 3 + c4] = (c4 == 0) ? t0 : ((c4 == 1) ? t1 : t2);
        }
    }
    __syncthreads();
    if (t < 128) {
        unsigned a0 = mbuf[(t * 2 + 0) * 3 + 0];
        unsigned a1 = mbuf[(t * 2 + 0) * 3 + 1];
        unsigned a2 = mbuf[(t * 2 + 0) * 3 + 2];
        merge3(a0, a1, a2, mbuf[(t * 2 + 1) * 3 + 0],
               mbuf[(t * 2 + 1) * 3 + 1], mbuf[(t * 2 + 1) * 3 + 2]);
        unsigned* pp = part + (size_t)(m0 + t) * 96 + blockIdx.y * 3;
        pp[0] = a0; pp[1] = a1; pp[2] = a2;
    }
}

// ---------------- resolve: window-candidates -> exact numpy re-score ----------------
__global__ __launch_bounds__(256) void resolve(
    const unsigned* __restrict__ part, const float* __restrict__ z,
    const float* __restrict__ cb, const float* __restrict__ zn,
    const float* __restrict__ en, float* __restrict__ out_zq,
    float* __restrict__ out_idx)
{
    const int w = threadIdx.x >> 6, lane = threadIdx.x & 63;
    const int row = blockIdx.x * 4 + w;
    __shared__ unsigned candbuf[4][16];

    const unsigned* pr = part + (size_t)row * 96;
    const unsigned k1 = pr[lane];
    const unsigned k2 = (lane < 32) ? pr[64 + lane] : 0xFFFFFFFFu;
    unsigned vm = min(k1, k2);
    #pragma unroll
    for (int m = 1; m < 64; m <<= 1)
        vm = min(vm, (unsigned)__shfl_xor((int)vm, m, 64));
    const unsigned vlim = (vm >> 14) + 84u;
    const bool s1 = (k1 >> 14) <= vlim;
    const bool s2 = (lane < 32) && ((k2 >> 14) <= vlim);
    const unsigned long long b1 = __ballot(s1);
    const unsigned long long b2 = __ballot(s2);
    const unsigned long long below = (1ull << lane) - 1ull;
    const int pos1 = __popcll(b1 & below);
    const int pos2 = __popcll(b1) + __popcll(b2 & below);
    int ncand = __popcll(b1) + __popcll(b2);
    if (ncand > 16) ncand = 16;

    if (lane < 16) candbuf[w][lane] = 0;
    __syncthreads();
    if (s1 && pos1 < 16) candbuf[w][pos1] = k1 & 16383u;
    if (s2 && pos2 < 16) candbuf[w][pos2] = k2 & 16383u;
    __syncthreads();

    const int ci = lane >> 2, l = lane & 3;
    const bool act = ci < ncand;
    const unsigned idxc = candbuf[w][ci];
    const float* zb  = z + ((size_t)(row >> 10) * 256) * 1024 + (row & 1023);
    const float* cbr = cb + (size_t)idxc * 256;
    // numpy einsum SSE chain, lane l of 4: elements ch*16 + v*4 + l, v desc
    float s = 0.f;
    #pragma unroll
    for (int ch = 0; ch < 16; ++ch)
        #pragma unroll
        for (int v = 3; v >= 0; --v) {
            const int cd = ch * 16 + v * 4 + l;
            s = fa(fm(zb[(size_t)cd << 10], cbr[cd]), s);
        }
    const int base = lane & ~3;
    const float s0 = __shfl(s, base + 0, 64);
    const float sA = __shfl(s, base + 1, 64);
    const float sB = __shfl(s, base + 2, 64);
    const float sC = __shfl(s, base + 3, 64);
    const float cross = fa(fa(s0, sA), fa(sB, sC));
    const float d = fs(fa(zn[row], en[idxc]), fm(2.0f, cross));
    unsigned long long key = act
        ? (((unsigned long long)__float_as_uint(d) << 32) | idxc) : ~0ull;
    #pragma unroll
    for (int m = 1; m < 64; m <<= 1) {
        const unsigned long long o =
            (unsigned long long)__shfl_xor((long long)key, m, 64);
        if (o < key) key = o;
    }
    const int widx = (int)(key & 0xFFFFFFFFu);
    *(float4*)(out_zq + (size_t)row * 256 + lane * 4) =
        *(const float4*)(cb + (size_t)widx * 256 + lane * 4);
    if (lane == 0) out_idx[row] = (float)widx;
}

extern "C" void kernel_launch(void* const* d_in, const int* in_sizes, int n_in,
                              void* d_out, int out_size, void* d_ws, size_t ws_size,
                              hipStream_t stream) {
    const float* z  = (const float*)d_in[0];   // [16][256][32][32]
    const float* cb = (const float*)d_in[1];   // [16384][256]
    float* out = (float*)d_out;                // z_q (4194304 f32) then idx (16384 as f32)

    char* ws = (char*)d_ws;
    _Float16* zh = (_Float16*)ws;                                  // 8 MB
    _Float16* eh = (_Float16*)(ws + (size_t)8388608);              // 8 MB
    float* zn  = (float*)(ws + (size_t)16777216);                  // 64 KB
    float* en  = (float*)(ws + (size_t)16842752);                  // 64 KB
    unsigned* part = (unsigned*)(ws + (size_t)16908288);           // 6.29 MB

    prep_z<<<4160, 256, 0, stream>>>(z, zh, zn);
    prep_e<<<4160, 256, 0, stream>>>(cb, eh, en);
    gemm_top3<<<dim3(128, 32), 256, 0, stream>>>(zh, eh, en, part);
    resolve<<<4096, 256, 0, stream>>>(part, z, cb, zn, en, out,
                                      out + (size_t)NQ * DIM);
}

// Round 8
// 337.268 us; speedup vs baseline: 5.1318x; 1.1123x over previous
//
#include <hip/hip_runtime.h>

// VQ nearest-codebook. Reference = numpy float32 pipeline (verified bit-exact
// R2). fp16 MFMA GEMM (K=256): s*2^20 = en*2^20 - 128*acc, where
// acc = fp16(z).fp16(e*2^14) accumulated fp32 (score error sigma ~3e-7,
// far below the 84-unit resolve window). Per-row running top-3 keys per
// 512-col group, exact numpy-f32 re-score of window candidates.
// R8: K-chunk 32 -> 2x16KB ping-pong (32 KB LDS, ~3 blocks/CU vs 2);
// merged prep kernel; resolve stages z-row in LDS.
//
// ws: zh 8MB | eh 8MB | zn 64K | en 64K | part 6.3MB

#define NQ 16384
#define NE 16384
#define DIM 256

typedef __attribute__((ext_vector_type(8))) _Float16 half8;
typedef __attribute__((ext_vector_type(4))) float floatx4;

__device__ __forceinline__ float fm(float a, float b) { return __fmul_rn(a, b); }
__device__ __forceinline__ float fa(float a, float b) { return __fadd_rn(a, b); }
__device__ __forceinline__ float fs(float a, float b) { return __fsub_rn(a, b); }

#define GLOAD_LDS16(gp, lp)                                                  \
    __builtin_amdgcn_global_load_lds(                                        \
        (const __attribute__((address_space(1))) void*)(gp),                 \
        (__attribute__((address_space(3))) void*)(lp), 16, 0, 0)

// ---------- fused prep: z transpose->fp16, znorm, e->fp16, enorm ----------
// blocks [0,4096): z transpose 32x32 tiles
// blocks [4096,4160): znorm rows (numpy pairwise, strided z)
// blocks [4160,8256): e -> fp16(e*2^14)
// blocks [8256,8320): enorm rows (numpy pairwise, contiguous)
__global__ __launch_bounds__(256) void prep(const float* __restrict__ z,
                                            const float* __restrict__ cb,
                                            _Float16* __restrict__ zh,
                                            _Float16* __restrict__ eh,
                                            float* __restrict__ zn,
                                            float* __restrict__ en) {
    const int bid = blockIdx.x;
    const int t = threadIdx.x;
    if (bid < 4096) {
        __shared__ float tile[32][33];
        const int b  = bid >> 8;
        const int c0 = ((bid >> 5) & 7) * 32;
        const int n0 = (bid & 31) * 32;
        const int tx = t & 31, ty = t >> 5;           // 32 x 8
        const float* zb = z + (size_t)b * 256 * 1024;
        #pragma unroll
        for (int j = 0; j < 32; j += 8)
            tile[ty + j][tx] = zb[(size_t)(c0 + ty + j) * 1024 + n0 + tx];
        __syncthreads();
        #pragma unroll
        for (int j = 0; j < 32; j += 8)
            zh[(size_t)(b * 1024 + n0 + ty + j) * 256 + c0 + tx] =
                (_Float16)tile[tx][ty + j];
    } else if (bid < 4160) {
        // numpy pairwise_sum(x*x): strided z row (element c at z[b][c][hw])
        const int row = (bid - 4096) * 256 + t;
        const float* p = z + ((size_t)(row >> 10) * 256) * 1024 + (row & 1023);
        float half_[2];
        #pragma unroll
        for (int h = 0; h < 2; ++h) {
            const int c0 = h * 128;
            float r[8], v;
            #pragma unroll
            for (int j = 0; j < 8; j++) { v = p[(size_t)(c0 + j) << 10]; r[j] = fm(v, v); }
            #pragma unroll
            for (int i = 8; i < 128; i += 8)
                #pragma unroll
                for (int j = 0; j < 8; j++) {
                    v = p[(size_t)(c0 + i + j) << 10];
                    r[j] = fa(r[j], fm(v, v));
                }
            half_[h] = fa(fa(fa(r[0], r[1]), fa(r[2], r[3])),
                          fa(fa(r[4], r[5]), fa(r[6], r[7])));
        }
        zn[row] = fa(half_[0], half_[1]);
    } else if (bid < 8256) {
        const size_t i = ((size_t)(bid - 4160) * 256 + t) * 4;
        const float4 v = *(const float4*)(cb + i);
        _Float16 o[4] = { (_Float16)(v.x * 16384.0f), (_Float16)(v.y * 16384.0f),
                          (_Float16)(v.z * 16384.0f), (_Float16)(v.w * 16384.0f) };
        *(ushort4*)(eh + i) = *(const ushort4*)o;
    } else {
        const int row = (bid - 8256) * 256 + t;
        const float* p = cb + (size_t)row * DIM;
        float half_[2];
        #pragma unroll
        for (int h = 0; h < 2; ++h) {
            const float* q = p + h * 128;
            float r[8];
            #pragma unroll
            for (int j = 0; j < 8; j++) r[j] = fm(q[j], q[j]);
            #pragma unroll
            for (int i = 8; i < 128; i += 8)
                #pragma unroll
                for (int j = 0; j < 8; j++) r[j] = fa(r[j], fm(q[i + j], q[i + j]));
            half_[h] = fa(fa(fa(r[0], r[1]), fa(r[2], r[3])),
                          fa(fa(r[4], r[5]), fa(r[6], r[7])));
        }
        en[row] = fa(half_[0], half_[1]);
    }
}

// sorted-triple merge: (a,b sorted ascending) -> top-3 of union in a
__device__ __forceinline__ void merge3(unsigned& a0, unsigned& a1, unsigned& a2,
                                       unsigned b0, unsigned b1, unsigned b2) {
    const unsigned m0 = min(a0, b0);
    const unsigned x  = max(a0, b0);
    const unsigned p  = min(a1, b1);
    const unsigned q  = max(a1, b1);
    const unsigned m1 = min(x, p);
    const unsigned m2 = min(max(x, p), min(q, min(a2, b2)));
    a0 = m0; a1 = m1; a2 = m2;
}

// ---------------- MFMA GEMM (K=256 fp16) + per-row running top-3 keys ----------------
// grid (128 row-tiles, 32 col-groups of 512); block 256 = 4 waves (2x2 of 64x64).
// Flat 32-iter (sub,kb) loop over K-chunks of 32; ping-pong LDS
// (2 x [A 8KB | B 8KB] = 32 KB total); one barrier/chunk; DMA for chunk i+1
// issued right after the barrier of chunk i.
// LDS slot map (per 128x32 tile, 512 slots of 16B): data (row m, kgroup g)
// lives at slot s = m*4 + ((g + (m>>1)) & 3) -> frag ds_read_b128 lands
// exactly 8 lanes per bank-phase (optimal); DMA inverse: m = s>>2,
// g = ((s&3) - (m>>1)) & 3.
__global__ __launch_bounds__(256, 3) void gemm_top3(
    const _Float16* __restrict__ zh, const _Float16* __restrict__ eh,
    const float* __restrict__ en, unsigned* __restrict__ part)
{
    __shared__ __align__(16) _Float16 lds[2][8192];  // [buf][A 4096 | B 4096] fp16
    unsigned* mbuf = (unsigned*)&lds[0][0];          // overlay after last compute

    const int t = threadIdx.x;
    const int lane = t & 63, w = t >> 6;
    const int wr = w >> 1, wc = w & 1;
    const int q4 = lane >> 4, c4 = lane & 15;
    const int m0 = blockIdx.x * 128;
    const int g0 = blockIdx.y * 512;

    unsigned trip[16][3];                     // running sorted top-3 per (i,r)
    #pragma unroll
    for (int s = 0; s < 16; ++s)
        trip[s][0] = trip[s][1] = trip[s][2] = 0xFFFFFFFFu;

    // DMA slot geometry: 512 slots/tile, 2 per thread
    int sm[2], sg[2];
    #pragma unroll
    for (int p = 0; p < 2; ++p) {
        const int s = p * 256 + t;
        sm[p] = s >> 2;
        sg[p] = ((s & 3) - (sm[p] >> 1)) & 3;
    }
    const int ldsb = w * 64 * 8;              // wave-uniform dest base (fp16 elems)

    // prefetch chunk 0 into buf 0
    {
        #pragma unroll
        for (int p = 0; p < 2; ++p) {
            GLOAD_LDS16(zh + (size_t)(m0 + sm[p]) * 256 + sg[p] * 8,
                        &lds[0][(p * 256) * 8 + ldsb]);
            GLOAD_LDS16(eh + (size_t)(g0 + sm[p]) * 256 + sg[p] * 8,
                        &lds[0][4096 + (p * 256) * 8 + ldsb]);
        }
    }

    floatx4 acc[4][4];
    for (int it = 0; it < 32; ++it) {
        const int sub = it >> 3;
        const int buf = it & 1;
        const int n0 = g0 + sub * 128;

        if ((it & 7) == 0) {
            #pragma unroll
            for (int i = 0; i < 4; i++)
                #pragma unroll
                for (int j = 0; j < 4; j++) acc[i][j] = (floatx4){0.f, 0.f, 0.f, 0.f};
        }

        __syncthreads();   // drains DMA(it); all waves done reading buf^1

        if (it + 1 < 32) {
            const int subn = (it + 1) >> 3;
            const int kbn  = ((it + 1) & 7) * 32;
            const int n0n  = g0 + subn * 128;
            _Float16* dst = &lds[buf ^ 1][0];
            #pragma unroll
            for (int p = 0; p < 2; ++p) {
                GLOAD_LDS16(zh + (size_t)(m0 + sm[p]) * 256 + kbn + sg[p] * 8,
                            dst + (p * 256) * 8 + ldsb);
                GLOAD_LDS16(eh + (size_t)(n0n + sm[p]) * 256 + kbn + sg[p] * 8,
                            dst + 4096 + (p * 256) * 8 + ldsb);
            }
        }

        const _Float16* Ab = &lds[buf][0];
        const _Float16* Bb = &lds[buf][4096];
        {
            half8 a[4], b[4];
            #pragma unroll
            for (int i = 0; i < 4; ++i) {
                const int m  = wr * 64 + i * 16 + c4;
                const int sa = m * 4 + ((q4 + (m >> 1)) & 3);
                a[i] = *(const half8*)&Ab[sa * 8];
            }
            #pragma unroll
            for (int j = 0; j < 4; ++j) {
                const int n  = wc * 64 + j * 16 + c4;
                const int sb = n * 4 + ((q4 + (n >> 1)) & 3);
                b[j] = *(const half8*)&Bb[sb * 8];
            }
            #pragma unroll
            for (int i = 0; i < 4; ++i)
                #pragma unroll
                for (int j = 0; j < 4; ++j)
                    acc[i][j] = __builtin_amdgcn_mfma_f32_16x16x32_f16(
                        a[i], b[j], acc[i][j], 0, 0, 0);
        }

        if ((it & 7) == 7) {
            // ---- epilogue: 3-op keys + running top-3 (register-only) ----
            float en2[4]; unsigned cp[4];
            #pragma unroll
            for (int j = 0; j < 4; ++j) {
                const int col = n0 + wc * 64 + j * 16 + c4;
                en2[j] = en[col] * 1048576.0f;                 // en * 2^20
                cp[j]  = (131072u << 14) + (unsigned)col;
            }
            #pragma unroll
            for (int i = 0; i < 4; ++i)
                #pragma unroll
                for (int r = 0; r < 4; ++r) {
                    // s*2^20 = en*2^20 - 2*2^-14*2^20*acc = fma(acc,-128,en2)
                    const int v0 = (int)__builtin_fmaf(acc[i][0][r], -128.0f, en2[0]);
                    const int v1 = (int)__builtin_fmaf(acc[i][1][r], -128.0f, en2[1]);
                    const int v2 = (int)__builtin_fmaf(acc[i][2][r], -128.0f, en2[2]);
                    const int v3 = (int)__builtin_fmaf(acc[i][3][r], -128.0f, en2[3]);
                    const unsigned k0 = ((unsigned)v0 << 14) + cp[0];
                    const unsigned k1 = ((unsigned)v1 << 14) + cp[1];
                    const unsigned k2 = ((unsigned)v2 << 14) + cp[2];
                    const unsigned k3 = ((unsigned)v3 << 14) + cp[3];
                    const unsigned l01 = min(k0, k1), h01 = max(k0, k1);
                    const unsigned l23 = min(k2, k3), h23 = max(k2, k3);
                    const unsigned s0  = min(l01, l23);
                    const unsigned m1  = max(l01, l23), m2 = min(h01, h23);
                    const unsigned s1  = min(m1, m2),  s2 = max(m1, m2);
                    merge3(trip[i * 4 + r][0], trip[i * 4 + r][1], trip[i * 4 + r][2],
                           s0, s1, s2);
                }
        }
    }

    // ---- one cross-lane merge over c4 lanes (masks 1,2,4,8) ----
    // mbuf overlays lds[0]: last compute (it=31) read lds[1]; lds[0] dead.
    #pragma unroll
    for (int s = 0; s < 16; ++s) {
        unsigned t0 = trip[s][0], t1 = trip[s][1], t2 = trip[s][2];
        #pragma unroll
        for (int msk = 1; msk < 16; msk <<= 1) {
            const unsigned u0 = (unsigned)__shfl_xor((int)t0, msk, 64);
            const unsigned u1 = (unsigned)__shfl_xor((int)t1, msk, 64);
            const unsigned u2 = (unsigned)__shfl_xor((int)t2, msk, 64);
            merge3(t0, t1, t2, u0, u1, u2);
        }
        if (c4 < 3) {
            const int row = wr * 64 + (s >> 2) * 16 + q4 * 4 + (s & 3);
            mbuf[(row * 2 + wc) * 3 + c4] = (c4 == 0) ? t0 : ((c4 == 1) ? t1 : t2);
        }
    }
    __syncthreads();
    if (t < 128) {
        unsigned a0 = mbuf[(t * 2 + 0) * 3 + 0];
        unsigned a1 = mbuf[(t * 2 + 0) * 3 + 1];
        unsigned a2 = mbuf[(t * 2 + 0) * 3 + 2];
        merge3(a0, a1, a2, mbuf[(t * 2 + 1) * 3 + 0],
               mbuf[(t * 2 + 1) * 3 + 1], mbuf[(t * 2 + 1) * 3 + 2]);
        unsigned* pp = part + (size_t)(m0 + t) * 96 + blockIdx.y * 3;
        pp[0] = a0; pp[1] = a1; pp[2] = a2;
    }
}

// ---------------- resolve: window-candidates -> exact numpy re-score ----------------
__global__ __launch_bounds__(256) void resolve(
    const unsigned* __restrict__ part, const float* __restrict__ z,
    const float* __restrict__ cb, const float* __restrict__ zn,
    const float* __restrict__ en, float* __restrict__ out_zq,
    float* __restrict__ out_idx)
{
    const int w = threadIdx.x >> 6, lane = threadIdx.x & 63;
    const int row = blockIdx.x * 4 + w;
    __shared__ float zrow[4][256];
    __shared__ unsigned candbuf[4][16];

    const float* zb = z + ((size_t)(row >> 10) * 256) * 1024 + (row & 1023);
    #pragma unroll
    for (int k = 0; k < 4; ++k)
        zrow[w][lane + 64 * k] = zb[(size_t)(lane + 64 * k) << 10];

    const unsigned* pr = part + (size_t)row * 96;
    const unsigned k1 = pr[lane];
    const unsigned k2 = (lane < 32) ? pr[64 + lane] : 0xFFFFFFFFu;
    unsigned vm = min(k1, k2);
    #pragma unroll
    for (int m = 1; m < 64; m <<= 1)
        vm = min(vm, (unsigned)__shfl_xor((int)vm, m, 64));
    const unsigned vlim = (vm >> 14) + 84u;
    const bool s1 = (k1 >> 14) <= vlim;
    const bool s2 = (lane < 32) && ((k2 >> 14) <= vlim);
    const unsigned long long b1 = __ballot(s1);
    const unsigned long long b2 = __ballot(s2);
    const unsigned long long below = (1ull << lane) - 1ull;
    const int pos1 = __popcll(b1 & below);
    const int pos2 = __popcll(b1) + __popcll(b2 & below);
    int ncand = __popcll(b1) + __popcll(b2);
    if (ncand > 16) ncand = 16;

    if (lane < 16) candbuf[w][lane] = 0;
    __syncthreads();
    if (s1 && pos1 < 16) candbuf[w][pos1] = k1 & 16383u;
    if (s2 && pos2 < 16) candbuf[w][pos2] = k2 & 16383u;
    __syncthreads();

    const int ci = lane >> 2, l = lane & 3;
    const bool act = ci < ncand;
    const unsigned idxc = candbuf[w][ci];
    const float* cbr = cb + (size_t)idxc * 256;
    // numpy einsum SSE chain, lane l of 4: elements ch*16 + v*4 + l, v desc
    float s = 0.f;
    #pragma unroll
    for (int ch = 0; ch < 16; ++ch)
        #pragma unroll
        for (int v = 3; v >= 0; --v) {
            const int cd = ch * 16 + v * 4 + l;
            s = fa(fm(zrow[w][cd], cbr[cd]), s);
        }
    const int base = lane & ~3;
    const float s0 = __shfl(s, base + 0, 64);
    const float sA = __shfl(s, base + 1, 64);
    const float sB = __shfl(s, base + 2, 64);
    const float sC = __shfl(s, base + 3, 64);
    const float cross = fa(fa(s0, sA), fa(sB, sC));
    const float d = fs(fa(zn[row], en[idxc]), fm(2.0f, cross));
    unsigned long long key = act
        ? (((unsigned long long)__float_as_uint(d) << 32) | idxc) : ~0ull;
    #pragma unroll
    for (int m = 1; m < 64; m <<= 1) {
        const unsigned long long o =
            (unsigned long long)__shfl_xor((long long)key, m, 64);
        if (o < key) key = o;
    }
    const int widx = (int)(key & 0xFFFFFFFFu);
    *(float4*)(out_zq + (size_t)row * 256 + lane * 4) =
        *(const float4*)(cb + (size_t)widx * 256 + lane * 4);
    if (lane == 0) out_idx[row] = (float)widx;
}

extern "C" void kernel_launch(void* const* d_in, const int* in_sizes, int n_in,
                              void* d_out, int out_size, void* d_ws, size_t ws_size,
                              hipStream_t stream) {
    const float* z  = (const float*)d_in[0];   // [16][256][32][32]
    const float* cb = (const float*)d_in[1];   // [16384][256]
    float* out = (float*)d_out;                // z_q (4194304 f32) then idx (16384 as f32)

    char* ws = (char*)d_ws;
    _Float16* zh = (_Float16*)ws;                                  // 8 MB
    _Float16* eh = (_Float16*)(ws + (size_t)8388608);              // 8 MB
    float* zn  = (float*)(ws + (size_t)16777216);                  // 64 KB
    float* en  = (float*)(ws + (size_t)16842752);                  // 64 KB
    unsigned* part = (unsigned*)(ws + (size_t)16908288);           // 6.29 MB

    prep<<<8320, 256, 0, stream>>>(z, cb, zh, eh, zn, en);
    gemm_top3<<<dim3(128, 32), 256, 0, stream>>>(zh, eh, en, part);
    resolve<<<4096, 256, 0, stream>>>(part, z, cb, zn, en, out,
                                      out + (size_t)NQ * DIM);
}